// Round 1
// baseline (4322.762 us; speedup 1.0000x reference)
//
#include <hip/hip_runtime.h>
#include <hip/hip_bf16.h>
#include <math.h>

// Problem dims
#define DD 384
#define NHD 8
#define DHD 48
#define LL 4
#define NB 32768
#define FFH 1536
#define LDA 392   // padded LDS stride (bf16 elems) for 384-wide tiles: +8 => 16B pad, ~2-way banks
#define LDF 264   // padded stride for 256-wide FFN chunk tile
#define LDP 388   // fp32 pooled stride
#define EPS 1e-5f

typedef short bf16x8 __attribute__((ext_vector_type(8)));
typedef float f32x4 __attribute__((ext_vector_type(4)));
typedef unsigned short u16;
typedef unsigned int u32;

__device__ __forceinline__ u16 f2b(float f){           // fp32 -> bf16 RNE
  u32 u = __builtin_bit_cast(u32, f);
  u += 0x7FFFu + ((u >> 16) & 1u);
  return (u16)(u >> 16);
}
__device__ __forceinline__ float b2f(u16 h){ u32 u = ((u32)h) << 16; return __builtin_bit_cast(float, u); }

__device__ __forceinline__ bf16x8 ldfrag(const u16* p){
  uint4 q = *reinterpret_cast<const uint4*>(p);
  return __builtin_bit_cast(bf16x8, q);
}

// fp32 -> bf16 weight conversion (prepass; weights stay hot in L2/L3)
extern "C" __global__ void wconv(const float* __restrict__ src, u16* __restrict__ dst, int n){
  int i = blockIdx.x * 256 + threadIdx.x;
  if (i < n) dst[i] = f2b(src[i]);
}

// ---------------------------------------------------------------------------
// K1: cross-attn collapses to  h1[b,l,:] = LN1( (x@wv^T+bv)@wout^T+bout + lat[l] )
// block: 512 thr (8 waves), 64 batch rows. waves: m-tile = w&3, N-half = w>>2
// ---------------------------------------------------------------------------
extern "C" __global__ void __launch_bounds__(512, 2)
k1_ca(const float* __restrict__ x, const float* __restrict__ latents,
      const float* __restrict__ ca_b_in, const float* __restrict__ ca_b_out,
      const float* __restrict__ n1g, const float* __restrict__ n1b,
      const u16* __restrict__ wv, const u16* __restrict__ wout,
      u16* __restrict__ h1g)
{
  extern __shared__ char smem[];
  u16* xb = (u16*)smem;           // [64][LDA]  x tile (bf16); later reused for ca
  u16* vb = xb + 64 * LDA;        // [64][LDA]  v tile
  const int tid = threadIdx.x, lane = tid & 63, w = tid >> 6;
  const int lr = lane & 15, lk = lane >> 4;
  const int b0 = blockIdx.x * 64;

  for (int i = tid; i < 64 * 96; i += 512){
    int r = i / 96, c4 = i % 96;
    float4 f = reinterpret_cast<const float4*>(x + (size_t)(b0 + r) * DD)[c4];
    u16* d = &xb[r * LDA + c4 * 4];
    d[0] = f2b(f.x); d[1] = f2b(f.y); d[2] = f2b(f.z); d[3] = f2b(f.w);
  }
  __syncthreads();

  const int m0 = (w & 3) * 16, nh = w >> 2;

  // GEMM1: vb = xb @ wv^T + bv
  {
    bf16x8 af[12];
    const u16* ap = &xb[(m0 + lr) * LDA + lk * 8];
    #pragma unroll
    for (int kk = 0; kk < 12; kk++) af[kk] = ldfrag(ap + kk * 32);
    for (int nt = nh * 12; nt < nh * 12 + 12; nt++){
      int n0 = nt * 16;
      f32x4 acc = {0.f, 0.f, 0.f, 0.f};
      const u16* bp = &wv[(size_t)(n0 + lr) * DD + lk * 8];
      #pragma unroll
      for (int kk = 0; kk < 12; kk++)
        acc = __builtin_amdgcn_mfma_f32_16x16x32_bf16(af[kk], ldfrag(bp + kk * 32), acc, 0, 0, 0);
      float bias = ca_b_in[768 + n0 + lr];
      #pragma unroll
      for (int r = 0; r < 4; r++)
        vb[(m0 + lk * 4 + r) * LDA + n0 + lr] = f2b(acc[r] + bias);
    }
  }
  __syncthreads();
  // GEMM2: ca (into xb) = vb @ wout^T + bout
  {
    bf16x8 af[12];
    const u16* ap = &vb[(m0 + lr) * LDA + lk * 8];
    #pragma unroll
    for (int kk = 0; kk < 12; kk++) af[kk] = ldfrag(ap + kk * 32);
    for (int nt = nh * 12; nt < nh * 12 + 12; nt++){
      int n0 = nt * 16;
      f32x4 acc = {0.f, 0.f, 0.f, 0.f};
      const u16* bp = &wout[(size_t)(n0 + lr) * DD + lk * 8];
      #pragma unroll
      for (int kk = 0; kk < 12; kk++)
        acc = __builtin_amdgcn_mfma_f32_16x16x32_bf16(af[kk], ldfrag(bp + kk * 32), acc, 0, 0, 0);
      float bias = ca_b_out[n0 + lr];
      #pragma unroll
      for (int r = 0; r < 4; r++)
        xb[(m0 + lk * 4 + r) * LDA + n0 + lr] = f2b(acc[r] + bias);
    }
  }
  __syncthreads();
  // LN1 over (ca + lat[l]) per (row,l); one wave per row-LN
  for (int idx = w; idx < 64 * LL; idx += 8){
    int l = idx >> 6, r = idx & 63;
    float vals[6]; float s1 = 0.f, s2 = 0.f;
    #pragma unroll
    for (int j = 0; j < 6; j++){
      int c = lane + 64 * j;
      float xv = b2f(xb[r * LDA + c]) + latents[l * DD + c];
      vals[j] = xv; s1 += xv; s2 += xv * xv;
    }
    #pragma unroll
    for (int off = 32; off > 0; off >>= 1){ s1 += __shfl_xor(s1, off); s2 += __shfl_xor(s2, off); }
    float mean = s1 * (1.f / DD);
    float var  = s2 * (1.f / DD) - mean * mean;
    float rstd = rsqrtf(var + EPS);
    size_t orow = ((size_t)(b0 + r) * LL + l) * DD;
    #pragma unroll
    for (int j = 0; j < 6; j++){
      int c = lane + 64 * j;
      h1g[orow + c] = f2b((vals[j] - mean) * rstd * n1g[c] + n1b[c]);
    }
  }
}

// ---------------------------------------------------------------------------
// K2: self-attn over L=4 + out-proj + residual + LN2 (in place on hg)
// block: 512 thr, 16 batches (64 token rows)
// ---------------------------------------------------------------------------
extern "C" __global__ void __launch_bounds__(512, 2)
k2_sa(const float* __restrict__ sa_b_in, const float* __restrict__ sa_b_out,
      const float* __restrict__ n2g, const float* __restrict__ n2b,
      const u16* __restrict__ wqkv, const u16* __restrict__ wo,
      u16* __restrict__ hg)
{
  extern __shared__ char smem[];
  u16*   ht = (u16*)smem;                       // [64][LDA]  h1 tile; becomes pre-LN2
  float* qf = (float*)(smem + 64 * LDA * 2);    // [64][52]
  float* kf = qf + 64 * 52;
  float* vf = kf + 64 * 52;
  u16*   ob = (u16*)(vf + 64 * 52);             // [64][LDA]  attn output (bf16)
  const int tid = threadIdx.x, lane = tid & 63, w = tid >> 6;
  const int lr = lane & 15, lk = lane >> 4;
  const int b0 = blockIdx.x * 16;
  const size_t t0 = (size_t)b0 * 4;

  for (int i = tid; i < 3072; i += 512){
    int r = i / 48, c8 = (i % 48) * 8;
    *reinterpret_cast<uint4*>(&ht[r * LDA + c8]) =
      *reinterpret_cast<const uint4*>(&hg[(t0 + r) * DD + c8]);
  }
  __syncthreads();

  const int m0 = (w & 3) * 16, nh = w >> 2;
  bf16x8 af[12];                                 // whole wave M-tile of h1, reused for all heads
  { const u16* ap = &ht[(m0 + lr) * LDA + lk * 8];
    #pragma unroll
    for (int kk = 0; kk < 12; kk++) af[kk] = ldfrag(ap + kk * 32); }

  for (int hh = 0; hh < NHD; hh++){
    // qkv projections for this head (9 16-col tiles: q0..2,k0..2,v0..2)
    for (int nt = nh; nt < 9; nt += 2){
      int op = nt / 3, sub = nt % 3;
      int wrow = op * DD + hh * DHD + sub * 16;
      f32x4 acc = {0.f, 0.f, 0.f, 0.f};
      const u16* bp = &wqkv[(size_t)(wrow + lr) * DD + lk * 8];
      #pragma unroll
      for (int kk = 0; kk < 12; kk++)
        acc = __builtin_amdgcn_mfma_f32_16x16x32_bf16(af[kk], ldfrag(bp + kk * 32), acc, 0, 0, 0);
      float bias = sa_b_in[wrow + lr];
      float* dst = (op == 0) ? qf : (op == 1) ? kf : vf;
      int c = sub * 16 + lr;
      #pragma unroll
      for (int r = 0; r < 4; r++)
        dst[(m0 + lk * 4 + r) * 52 + c] = acc[r] + bias;
    }
    __syncthreads();
    // tiny attention: 32 threads per batch
    {
      int tb = tid >> 5, t = tid & 31;
      int qr = t & 3, cg = t >> 2;
      int rq = tb * 4 + qr;
      const float scale = 0.14433756729740643f;  // 1/sqrt(48)
      float s[4];
      #pragma unroll
      for (int kl = 0; kl < 4; kl++){
        float acc = 0.f;
        const float* qp = &qf[rq * 52];
        const float* kp = &kf[(tb * 4 + kl) * 52];
        #pragma unroll
        for (int d2 = 0; d2 < 48; d2++) acc += qp[d2] * kp[d2];
        s[kl] = acc * scale;
      }
      float m = fmaxf(fmaxf(s[0], s[1]), fmaxf(s[2], s[3]));
      float e0 = expf(s[0] - m), e1 = expf(s[1] - m), e2 = expf(s[2] - m), e3 = expf(s[3] - m);
      float rs = 1.f / (e0 + e1 + e2 + e3);
      #pragma unroll
      for (int cc = 0; cc < 6; cc++){
        int c = cg * 6 + cc;
        float o = e0 * rs * vf[(tb * 4 + 0) * 52 + c] + e1 * rs * vf[(tb * 4 + 1) * 52 + c]
                + e2 * rs * vf[(tb * 4 + 2) * 52 + c] + e3 * rs * vf[(tb * 4 + 3) * 52 + c];
        ob[rq * LDA + hh * DHD + c] = f2b(o);
      }
    }
    __syncthreads();
  }
  // out-proj + residual -> pre-LN2 written in place into ht
  bf16x8 af2[12];
  { const u16* ap = &ob[(m0 + lr) * LDA + lk * 8];
    #pragma unroll
    for (int kk = 0; kk < 12; kk++) af2[kk] = ldfrag(ap + kk * 32); }
  for (int nt = nh * 12; nt < nh * 12 + 12; nt++){
    int n0 = nt * 16;
    f32x4 acc = {0.f, 0.f, 0.f, 0.f};
    const u16* bp = &wo[(size_t)(n0 + lr) * DD + lk * 8];
    #pragma unroll
    for (int kk = 0; kk < 12; kk++)
      acc = __builtin_amdgcn_mfma_f32_16x16x32_bf16(af2[kk], ldfrag(bp + kk * 32), acc, 0, 0, 0);
    float bias = sa_b_out[n0 + lr];
    #pragma unroll
    for (int r = 0; r < 4; r++){
      int row = m0 + lk * 4 + r, c = n0 + lr;
      float v = acc[r] + bias + b2f(ht[row * LDA + c]);
      ht[row * LDA + c] = f2b(v);
    }
  }
  __syncthreads();
  // LN2 -> global (in-place h buffer)
  for (int r = w; r < 64; r += 8){
    float vals[6]; float s1 = 0.f, s2 = 0.f;
    #pragma unroll
    for (int j = 0; j < 6; j++){
      int c = lane + 64 * j;
      float xv = b2f(ht[r * LDA + c]);
      vals[j] = xv; s1 += xv; s2 += xv * xv;
    }
    #pragma unroll
    for (int off = 32; off > 0; off >>= 1){ s1 += __shfl_xor(s1, off); s2 += __shfl_xor(s2, off); }
    float mean = s1 * (1.f / DD), var = s2 * (1.f / DD) - mean * mean, rstd = rsqrtf(var + EPS);
    #pragma unroll
    for (int j = 0; j < 6; j++){
      int c = lane + 64 * j;
      hg[(t0 + r) * DD + c] = f2b((vals[j] - mean) * rstd * n2g[c] + n2b[c]);
    }
  }
}

// ---------------------------------------------------------------------------
// K3: FFN (hidden chunked by 256, ff acc persistent in VGPRs) + LN3 + pool + gate
// block: 512 thr, 16 batches (64 token rows)
// ---------------------------------------------------------------------------
extern "C" __global__ void __launch_bounds__(512, 2)
k3_ffn(const float* __restrict__ ffn_b1, const float* __restrict__ ffn_b2,
       const float* __restrict__ n3g, const float* __restrict__ n3b,
       const float* __restrict__ gate_b,
       const u16* __restrict__ w1, const u16* __restrict__ w2, const u16* __restrict__ wg,
       const u16* __restrict__ hg, float* __restrict__ out)
{
  extern __shared__ char smem[];
  u16*   ht = (u16*)smem;                        // [64][LDA] h tile; becomes pre-LN3 then h3
  u16*   tc = ht + 64 * LDA;                     // [64][LDF] gelu(h@w1c^T) chunk
  u16*   pb = tc + 64 * LDF;                     // [16][LDA] pooled bf16
  float* pf = (float*)(pb + 16 * LDA);           // [16][LDP] pooled fp32
  const int tid = threadIdx.x, lane = tid & 63, w = tid >> 6;
  const int lr = lane & 15, lk = lane >> 4;
  const int b0 = blockIdx.x * 16;
  const size_t t0 = (size_t)b0 * 4;

  for (int i = tid; i < 3072; i += 512){
    int r = i / 48, c8 = (i % 48) * 8;
    *reinterpret_cast<uint4*>(&ht[r * LDA + c8]) =
      *reinterpret_cast<const uint4*>(&hg[(t0 + r) * DD + c8]);
  }
  __syncthreads();

  const int m0 = (w & 3) * 16, nh = w >> 2;
  bf16x8 af[12];
  { const u16* ap = &ht[(m0 + lr) * LDA + lk * 8];
    #pragma unroll
    for (int kk = 0; kk < 12; kk++) af[kk] = ldfrag(ap + kk * 32); }

  f32x4 ffacc[12];
  #pragma unroll
  for (int i = 0; i < 12; i++) ffacc[i] = {0.f, 0.f, 0.f, 0.f};

  for (int fc = 0; fc < 6; fc++){
    f32x4 tacc[8];
    #pragma unroll
    for (int i = 0; i < 8; i++) tacc[i] = {0.f, 0.f, 0.f, 0.f};
    #pragma unroll 1
    for (int kk = 0; kk < 12; kk++){
      bf16x8 a = af[kk];
      #pragma unroll
      for (int t = 0; t < 8; t++){
        int hrow = fc * 256 + (nh * 8 + t) * 16 + lr;
        tacc[t] = __builtin_amdgcn_mfma_f32_16x16x32_bf16(
                    a, ldfrag(&w1[(size_t)hrow * DD + kk * 32 + lk * 8]), tacc[t], 0, 0, 0);
      }
    }
    #pragma unroll
    for (int t = 0; t < 8; t++){
      int cl = (nh * 8 + t) * 16 + lr;
      float bias = ffn_b1[fc * 256 + cl];
      #pragma unroll
      for (int r = 0; r < 4; r++){
        float v = tacc[t][r] + bias;
        float g = 0.5f * v * (1.f + erff(v * 0.70710678118f));   // exact gelu
        tc[(m0 + lk * 4 + r) * LDF + cl] = f2b(g);
      }
    }
    __syncthreads();
    #pragma unroll 1
    for (int kk = 0; kk < 8; kk++){
      bf16x8 a2 = ldfrag(&tc[(m0 + lr) * LDF + kk * 32 + lk * 8]);
      #pragma unroll
      for (int nt = 0; nt < 12; nt++){
        int n0 = nh * 192 + nt * 16;
        ffacc[nt] = __builtin_amdgcn_mfma_f32_16x16x32_bf16(
                      a2, ldfrag(&w2[(size_t)(n0 + lr) * FFH + fc * 256 + kk * 32 + lk * 8]),
                      ffacc[nt], 0, 0, 0);
      }
    }
    __syncthreads();
  }
  // + b2 + residual -> pre-LN3 in place
  #pragma unroll
  for (int nt = 0; nt < 12; nt++){
    int c = nh * 192 + nt * 16 + lr;
    float b2v = ffn_b2[c];
    #pragma unroll
    for (int r = 0; r < 4; r++){
      int row = m0 + lk * 4 + r;
      float v = ffacc[nt][r] + b2v + b2f(ht[row * LDA + c]);
      ht[row * LDA + c] = f2b(v);
    }
  }
  __syncthreads();
  // LN3 in place
  for (int r = w; r < 64; r += 8){
    float vals[6]; float s1 = 0.f, s2 = 0.f;
    #pragma unroll
    for (int j = 0; j < 6; j++){
      int c = lane + 64 * j;
      float xv = b2f(ht[r * LDA + c]);
      vals[j] = xv; s1 += xv; s2 += xv * xv;
    }
    #pragma unroll
    for (int off = 32; off > 0; off >>= 1){ s1 += __shfl_xor(s1, off); s2 += __shfl_xor(s2, off); }
    float mean = s1 * (1.f / DD), var = s2 * (1.f / DD) - mean * mean, rstd = rsqrtf(var + EPS);
    #pragma unroll
    for (int j = 0; j < 6; j++){
      int c = lane + 64 * j;
      ht[r * LDA + c] = f2b((vals[j] - mean) * rstd * n3g[c] + n3b[c]);
    }
  }
  __syncthreads();
  // pool over L
  for (int i = tid; i < 16 * DD; i += 512){
    int tb = i / DD, c = i % DD;
    float p = 0.25f * (b2f(ht[(tb * 4 + 0) * LDA + c]) + b2f(ht[(tb * 4 + 1) * LDA + c])
                     + b2f(ht[(tb * 4 + 2) * LDA + c]) + b2f(ht[(tb * 4 + 3) * LDA + c]));
    pf[tb * LDP + c] = p;
    pb[tb * LDA + c] = f2b(p);
  }
  __syncthreads();
  // gate gemm (M=16) + sigmoid + multiply + store fp32
  {
    bf16x8 ag[12];
    const u16* ap = &pb[lr * LDA + lk * 8];
    #pragma unroll
    for (int kk = 0; kk < 12; kk++) ag[kk] = ldfrag(ap + kk * 32);
    for (int nt = w * 3; nt < w * 3 + 3; nt++){
      int n0 = nt * 16;
      f32x4 acc = {0.f, 0.f, 0.f, 0.f};
      const u16* bp = &wg[(size_t)(n0 + lr) * DD + lk * 8];
      #pragma unroll
      for (int kk = 0; kk < 12; kk++)
        acc = __builtin_amdgcn_mfma_f32_16x16x32_bf16(ag[kk], ldfrag(bp + kk * 32), acc, 0, 0, 0);
      float gbv = gate_b[n0 + lr];
      #pragma unroll
      for (int r = 0; r < 4; r++){
        int batch = lk * 4 + r;
        float g = 1.f / (1.f + expf(-(acc[r] + gbv)));
        out[(size_t)(b0 + batch) * DD + n0 + lr] = pf[batch * LDP + n0 + lr] * g;
      }
    }
  }
}

// ---------------------------------------------------------------------------
// host launch
// ---------------------------------------------------------------------------
#define OFF_WV     0
#define OFF_WOUT   147456
#define OFF_SAWIN  294912
#define OFF_SAWOUT 737280
#define OFF_W1     884736
#define OFF_W2     1474560
#define OFF_WG     2064384
#define OFF_H      2211840   // ushort index; h buffer: 32768*4*384 bf16

extern "C" void kernel_launch(void* const* d_in, const int* in_sizes, int n_in,
                              void* d_out, int out_size, void* d_ws, size_t ws_size,
                              hipStream_t stream)
{
  const float* x        = (const float*)d_in[0];
  const float* latents  = (const float*)d_in[1];
  const float* ca_w_in  = (const float*)d_in[2];
  const float* ca_b_in  = (const float*)d_in[3];
  const float* ca_w_out = (const float*)d_in[4];
  const float* ca_b_out = (const float*)d_in[5];
  const float* sa_w_in  = (const float*)d_in[6];
  const float* sa_b_in  = (const float*)d_in[7];
  const float* sa_w_out = (const float*)d_in[8];
  const float* sa_b_out = (const float*)d_in[9];
  const float* n1g = (const float*)d_in[10];
  const float* n1b = (const float*)d_in[11];
  const float* n2g = (const float*)d_in[12];
  const float* n2b = (const float*)d_in[13];
  const float* n3g = (const float*)d_in[14];
  const float* n3b = (const float*)d_in[15];
  const float* w1f = (const float*)d_in[16];
  const float* b1  = (const float*)d_in[17];
  const float* w2f = (const float*)d_in[18];
  const float* b2  = (const float*)d_in[19];
  const float* wgf = (const float*)d_in[20];
  const float* gb  = (const float*)d_in[21];

  u16* ws = (u16*)d_ws;
  u16* wv     = ws + OFF_WV;
  u16* wout   = ws + OFF_WOUT;
  u16* sawin  = ws + OFF_SAWIN;
  u16* sawout = ws + OFF_SAWOUT;
  u16* w1     = ws + OFF_W1;
  u16* w2     = ws + OFF_W2;
  u16* wg     = ws + OFF_WG;
  u16* h      = ws + OFF_H;

  wconv<<<dim3((147456 + 255) / 256), dim3(256), 0, stream>>>(ca_w_in + 768 * 384, wv, 147456);
  wconv<<<dim3((147456 + 255) / 256), dim3(256), 0, stream>>>(ca_w_out, wout, 147456);
  wconv<<<dim3((442368 + 255) / 256), dim3(256), 0, stream>>>(sa_w_in, sawin, 442368);
  wconv<<<dim3((147456 + 255) / 256), dim3(256), 0, stream>>>(sa_w_out, sawout, 147456);
  wconv<<<dim3((589824 + 255) / 256), dim3(256), 0, stream>>>(w1f, w1, 589824);
  wconv<<<dim3((589824 + 255) / 256), dim3(256), 0, stream>>>(w2f, w2, 589824);
  wconv<<<dim3((147456 + 255) / 256), dim3(256), 0, stream>>>(wgf, wg, 147456);

  const int SM1 = 2 * 64 * LDA * 2;                                   // 100352
  const int SM2 = 64 * LDA * 2 + 3 * 64 * 52 * 4 + 64 * LDA * 2;      // 140288
  const int SM3 = 64 * LDA * 2 + 64 * LDF * 2 + 16 * LDA * 2 + 16 * LDP * 4; // 121344
  (void)hipFuncSetAttribute((const void*)k1_ca,  hipFuncAttributeMaxDynamicSharedMemorySize, SM1);
  (void)hipFuncSetAttribute((const void*)k2_sa,  hipFuncAttributeMaxDynamicSharedMemorySize, SM2);
  (void)hipFuncSetAttribute((const void*)k3_ffn, hipFuncAttributeMaxDynamicSharedMemorySize, SM3);

  k1_ca<<<dim3(512),  dim3(512), SM1, stream>>>(x, latents, ca_b_in, ca_b_out, n1g, n1b, wv, wout, h);
  k2_sa<<<dim3(2048), dim3(512), SM2, stream>>>(sa_b_in, sa_b_out, n2g, n2b, sawin, sawout, h);
  k3_ffn<<<dim3(2048), dim3(512), SM3, stream>>>(b1, b2, n3g, n3b, gb, w1, w2, wg, h, (float*)d_out);

  (void)in_sizes; (void)n_in; (void)out_size; (void)ws_size;
}